// Round 4
// baseline (15487.411 us; speedup 1.0000x reference)
//
#include <hip/hip_runtime.h>
#include <hip/hip_fp16.h>
#include <math.h>

#define HDIM 2048
#define G4   (4 * HDIM)   // 8192 gate rows
#define NBLK 256          // persistent grid: 1 block per CU

// NOTE: __builtin_amdgcn_cvt_pkrtz / __builtin_amdgcn_fdot2 use the __fp16
// vector type, NOT _Float16 (they don't implicitly convert).
typedef __fp16 h2_t __attribute__((ext_vector_type(2)));

// ---------------------------------------------------------------------------
// prep: b_sum = b_ih + b_hh ; c = 0 ; barrier counters = 0
// ---------------------------------------------------------------------------
__global__ __launch_bounds__(256) void prep_small(const float* __restrict__ bih,
                                                  const float* __restrict__ bhh,
                                                  float* __restrict__ bsum,
                                                  float* __restrict__ c,
                                                  int* __restrict__ bar) {
    int i = blockIdx.x * blockDim.x + threadIdx.x;
    if (i < G4) bsum[i] = bih[i] + bhh[i];
    if (i < HDIM) c[i] = 0.0f;
    if (i < 1024) bar[i] = 0;
}

// ---------------------------------------------------------------------------
// prep: W_sum = fp16(W_ih + W_hh)
// ---------------------------------------------------------------------------
__global__ __launch_bounds__(256) void prep_wsum_h(const float* __restrict__ Wih,
                                                   const float* __restrict__ Whh,
                                                   __half* __restrict__ Wsum) {
    const int n8 = (G4 * HDIM) / 8;
    int idx = blockIdx.x * blockDim.x + threadIdx.x;
    int stride = gridDim.x * blockDim.x;
    const float4* a = (const float4*)Wih;
    const float4* b = (const float4*)Whh;
    for (int i = idx; i < n8; i += stride) {
        float4 a0 = a[2 * i], a1 = a[2 * i + 1];
        float4 b0 = b[2 * i], b1 = b[2 * i + 1];
        __half h[8];
        h[0] = __float2half(a0.x + b0.x);
        h[1] = __float2half(a0.y + b0.y);
        h[2] = __float2half(a0.z + b0.z);
        h[3] = __float2half(a0.w + b0.w);
        h[4] = __float2half(a1.x + b1.x);
        h[5] = __float2half(a1.y + b1.y);
        h[6] = __float2half(a1.z + b1.z);
        h[7] = __float2half(a1.w + b1.w);
        ((uint4*)Wsum)[i] = *(const uint4*)h;
    }
}

// ---------------------------------------------------------------------------
// t=0 step, exact fp32: gates = X @ W_ih.T + bsum (h0 = 0). Writes h->out[0],
// c->c[]. Same structure as round 2 (verified).
// ---------------------------------------------------------------------------
__global__ __launch_bounds__(256) void lstm_step_f32(const float* __restrict__ x,
                                                     const float* __restrict__ W,
                                                     const float* __restrict__ bsum,
                                                     float* __restrict__ c,
                                                     float* __restrict__ h_out) {
    __shared__ float gates[4][8];
    const int tid  = threadIdx.x;
    const int wave = tid >> 6;
    const int lane = tid & 63;
    const int j0   = blockIdx.x * 8;

    float4 xv[8];
    const float4* xp = (const float4*)x;
#pragma unroll
    for (int k = 0; k < 8; ++k) xv[k] = xp[lane + 64 * k];

    float acc[8];
#pragma unroll
    for (int j8 = 0; j8 < 8; ++j8) {
        const int R = wave * HDIM + j0 + j8;
        const float4* wr = (const float4*)(W + (size_t)R * HDIM);
        float a = 0.0f;
#pragma unroll
        for (int k = 0; k < 8; ++k) {
            float4 wv = wr[lane + 64 * k];
            a += wv.x * xv[k].x + wv.y * xv[k].y + wv.z * xv[k].z + wv.w * xv[k].w;
        }
        acc[j8] = a;
    }
#pragma unroll
    for (int j8 = 0; j8 < 8; ++j8) {
        float a = acc[j8];
#pragma unroll
        for (int off = 32; off > 0; off >>= 1) a += __shfl_down(a, off, 64);
        if (lane == 0) gates[wave][j8] = a + bsum[wave * HDIM + j0 + j8];
    }
    __syncthreads();
    if (tid < 8) {
        const int j = j0 + tid;
        const float si = 1.0f / (1.0f + expf(-gates[0][tid]));
        const float sf = 1.0f / (1.0f + expf(-gates[1][tid]));
        const float so = 1.0f / (1.0f + expf(-gates[3][tid]));
        const float tg = tanhf(gates[2][tid]);
        const float cn = sf * 0.0f + si * tg;  // c0 = 0
        c[j]     = cn;
        h_out[j] = so * tanhf(cn);
    }
}

// ---------------------------------------------------------------------------
// Round-2 per-step fp16 kernel — kept as runtime fallback if the cooperative
// launch is rejected.
// ---------------------------------------------------------------------------
__global__ __launch_bounds__(256) void lstm_step_h(const float* __restrict__ x,
                                                   const __half* __restrict__ W,
                                                   const float* __restrict__ bsum,
                                                   float* __restrict__ c,
                                                   float* __restrict__ h_out) {
    __shared__ float gates[4][8];
    const int tid  = threadIdx.x;
    const int wave = tid >> 6;
    const int lane = tid & 63;
    const int j0   = blockIdx.x * 8;

    float xv[32];
    const float4* xp = (const float4*)x;
#pragma unroll
    for (int k = 0; k < 4; ++k) {
        float4 a = xp[k * 128 + lane * 2];
        float4 b = xp[k * 128 + lane * 2 + 1];
        xv[k * 8 + 0] = a.x; xv[k * 8 + 1] = a.y; xv[k * 8 + 2] = a.z; xv[k * 8 + 3] = a.w;
        xv[k * 8 + 4] = b.x; xv[k * 8 + 5] = b.y; xv[k * 8 + 6] = b.z; xv[k * 8 + 7] = b.w;
    }
    float acc[8];
#pragma unroll
    for (int j8 = 0; j8 < 8; ++j8) {
        const int R = wave * HDIM + j0 + j8;
        const uint4* wr = (const uint4*)(W + (size_t)R * HDIM);
        float a = 0.0f;
#pragma unroll
        for (int k = 0; k < 4; ++k) {
            uint4 wv = wr[k * 64 + lane];
            const __half* hh = (const __half*)&wv;
#pragma unroll
            for (int e = 0; e < 8; ++e)
                a = fmaf(__half2float(hh[e]), xv[k * 8 + e], a);
        }
        acc[j8] = a;
    }
#pragma unroll
    for (int j8 = 0; j8 < 8; ++j8) {
        float a = acc[j8];
#pragma unroll
        for (int off = 32; off > 0; off >>= 1) a += __shfl_down(a, off, 64);
        if (lane == 0) gates[wave][j8] = a + bsum[wave * HDIM + j0 + j8];
    }
    __syncthreads();
    if (tid < 8) {
        const int j = j0 + tid;
        const float si = 1.0f / (1.0f + expf(-gates[0][tid]));
        const float sf = 1.0f / (1.0f + expf(-gates[1][tid]));
        const float so = 1.0f / (1.0f + expf(-gates[3][tid]));
        const float tg = tanhf(gates[2][tid]);
        const float cn = sf * c[j] + si * tg;
        c[j]     = cn;
        h_out[j] = so * tanhf(cn);
    }
}

// ---------------------------------------------------------------------------
// Persistent cooperative kernel: steps 1..T-1 with W_sum resident in VGPRs.
// Grid 256 x 256 (1 block per CU). Block b owns h[8b..8b+8); wave q = gate q.
// Lane holds 8 rows x 32 cols of fp16 weights = 128 VGPRs, loaded once.
// Per step: read h_{t-1} (broadcast 8 KB), v_dot2_f32_f16 dot, shuffle-
// reduce, pointwise update (c in LDS), write h, device-scope counter
// barrier (bar[t]) for cross-XCD visibility.
// ---------------------------------------------------------------------------
__global__ __launch_bounds__(256, 1) void lstm_persist(const __half* __restrict__ W,
                                                       const float* __restrict__ bsum,
                                                       const float* __restrict__ c0,
                                                       float* __restrict__ out,
                                                       int* __restrict__ bar,
                                                       int T) {
    const int tid  = threadIdx.x;
    const int wave = tid >> 6;
    const int lane = tid & 63;
    const int j0   = blockIdx.x * 8;
    const int nb   = (int)gridDim.x;

    // One-time: weights into registers (8 rows x 4 uint4 = 128 VGPRs/lane).
    uint4 w[8][4];
#pragma unroll
    for (int j8 = 0; j8 < 8; ++j8) {
        const size_t R = (size_t)(wave * HDIM + j0 + j8);
        const uint4* wr = (const uint4*)(W + R * HDIM);
#pragma unroll
        for (int e = 0; e < 4; ++e) w[j8][e] = wr[lane + 64 * e];
    }
    float bias[8];
#pragma unroll
    for (int j8 = 0; j8 < 8; ++j8) bias[j8] = bsum[wave * HDIM + j0 + j8];

    __shared__ float c_sh[8];
    __shared__ float gates[4][8];
    if (tid < 8) c_sh[tid] = c0[j0 + tid];
    __syncthreads();

    for (int t = 1; t < T; ++t) {
        const float4* xp = (const float4*)(out + (size_t)(t - 1) * HDIM);

        float acc[8] = {0.f, 0.f, 0.f, 0.f, 0.f, 0.f, 0.f, 0.f};
#pragma unroll
        for (int e = 0; e < 4; ++e) {
            // This lane's 8 columns for chunk e: (lane + 64e)*8 .. +8
            float4 a = xp[(lane + 64 * e) * 2];
            float4 b = xp[(lane + 64 * e) * 2 + 1];
            h2_t xh[4];
#if __has_builtin(__builtin_amdgcn_cvt_pkrtz)
            xh[0] = __builtin_amdgcn_cvt_pkrtz(a.x, a.y);
            xh[1] = __builtin_amdgcn_cvt_pkrtz(a.z, a.w);
            xh[2] = __builtin_amdgcn_cvt_pkrtz(b.x, b.y);
            xh[3] = __builtin_amdgcn_cvt_pkrtz(b.z, b.w);
#else
            xh[0] = h2_t{(__fp16)a.x, (__fp16)a.y};
            xh[1] = h2_t{(__fp16)a.z, (__fp16)a.w};
            xh[2] = h2_t{(__fp16)b.x, (__fp16)b.y};
            xh[3] = h2_t{(__fp16)b.z, (__fp16)b.w};
#endif
#pragma unroll
            for (int j8 = 0; j8 < 8; ++j8) {
                const h2_t* wh = (const h2_t*)&w[j8][e];
#if __has_builtin(__builtin_amdgcn_fdot2)
                float s = acc[j8];
                s = __builtin_amdgcn_fdot2(wh[0], xh[0], s, false);
                s = __builtin_amdgcn_fdot2(wh[1], xh[1], s, false);
                s = __builtin_amdgcn_fdot2(wh[2], xh[2], s, false);
                s = __builtin_amdgcn_fdot2(wh[3], xh[3], s, false);
                acc[j8] = s;
#else
                float s = acc[j8];
#pragma unroll
                for (int p = 0; p < 4; ++p) {
                    s = fmaf((float)wh[p][0], (float)xh[p][0], s);
                    s = fmaf((float)wh[p][1], (float)xh[p][1], s);
                }
                acc[j8] = s;
#endif
            }
        }

#pragma unroll
        for (int j8 = 0; j8 < 8; ++j8) {
            float a = acc[j8];
#pragma unroll
            for (int off = 32; off > 0; off >>= 1) a += __shfl_down(a, off, 64);
            if (lane == 0) gates[wave][j8] = a + bias[j8];
        }
        __syncthreads();

        if (tid < 8) {
            const float si = 1.0f / (1.0f + expf(-gates[0][tid]));
            const float sf = 1.0f / (1.0f + expf(-gates[1][tid]));
            const float so = 1.0f / (1.0f + expf(-gates[3][tid]));
            const float tg = tanhf(gates[2][tid]);
            const float cn = sf * c_sh[tid] + si * tg;
            c_sh[tid] = cn;
            out[(size_t)t * HDIM + j0 + tid] = so * tanhf(cn);
        }
        __syncthreads();

        if (t + 1 < T) {
            if (tid == 0) {
                __threadfence();  // release: h visible device-wide
                __hip_atomic_fetch_add(&bar[t], 1, __ATOMIC_RELEASE,
                                       __HIP_MEMORY_SCOPE_AGENT);
                while (__hip_atomic_load(&bar[t], __ATOMIC_RELAXED,
                                         __HIP_MEMORY_SCOPE_AGENT) < nb)
                    __builtin_amdgcn_s_sleep(2);
            }
            __syncthreads();
            __threadfence();  // acquire: no stale h in L1/L2
        }
    }
}

// ---------------------------------------------------------------------------
extern "C" void kernel_launch(void* const* d_in, const int* in_sizes, int n_in,
                              void* d_out, int out_size, void* d_ws, size_t ws_size,
                              hipStream_t stream) {
    const float* X   = (const float*)d_in[0];
    const float* Wih = (const float*)d_in[1];
    const float* Whh = (const float*)d_in[2];
    const float* bih = (const float*)d_in[3];
    const float* bhh = (const float*)d_in[4];
    float* out = (float*)d_out;

    int T = out_size / HDIM;  // 512

    // ws: [W_sum fp16 33.55 MB][b_sum 32 KB][c 8 KB][bar 4 KB]
    const size_t wsum_bytes = (size_t)G4 * HDIM * sizeof(__half);
    char* ws = (char*)d_ws;
    __half* Wsum = (__half*)ws;
    float*  bsum = (float*)(ws + wsum_bytes);
    float*  c    = bsum + G4;
    int*    bar  = (int*)(c + HDIM);

    prep_small<<<(G4 + 255) / 256, 256, 0, stream>>>(bih, bhh, bsum, c, bar);
    prep_wsum_h<<<2048, 256, 0, stream>>>(Wih, Whh, Wsum);

    // t = 0: exact fp32, gates = X @ W_ih.T + b_sum.
    lstm_step_f32<<<256, 256, 0, stream>>>(X, Wih, bsum, c, out);

    // t >= 1: persistent cooperative kernel, weights in VGPRs.
    void* args[] = {(void*)&Wsum, (void*)&bsum, (void*)&c, (void*)&out,
                    (void*)&bar, (void*)&T};
    hipError_t err = hipLaunchCooperativeKernel((const void*)lstm_persist,
                                                dim3(NBLK), dim3(256), args, 0, stream);
    if (err != hipSuccess) {
        // Fallback: proven round-2 per-step loop.
        for (int t = 1; t < T; ++t) {
            const float* hprev = out + (size_t)(t - 1) * HDIM;
            float* hnext = out + (size_t)t * HDIM;
            lstm_step_h<<<256, 256, 0, stream>>>(hprev, Wsum, bsum, c, hnext);
        }
    }
}

// Round 5
// 2696.724 us; speedup vs baseline: 5.7430x; 5.7430x over previous
//
#include <hip/hip_runtime.h>
#include <hip/hip_fp16.h>
#include <math.h>

#define HDIM 2048
#define G4   (4 * HDIM)   // 8192 gate rows
#define NBLK 256          // persistent grid: 1 block per CU
#define NSLOT 1024        // h slots per buffer (2 fp16 per slot)

// __builtin_amdgcn_cvt_pkrtz / __builtin_amdgcn_fdot2 use the __fp16 vector
// type (NOT _Float16 — they don't implicitly convert).
typedef __fp16 h2_t __attribute__((ext_vector_type(2)));

// ---------------------------------------------------------------------------
// prep: b_sum = b_ih + b_hh ; c = 0 ; tagged h slots = 0 (tag 0 = invalid)
// ---------------------------------------------------------------------------
__global__ __launch_bounds__(256) void prep_small(const float* __restrict__ bih,
                                                  const float* __restrict__ bhh,
                                                  float* __restrict__ bsum,
                                                  float* __restrict__ c,
                                                  unsigned long long* __restrict__ slots) {
    int i = blockIdx.x * blockDim.x + threadIdx.x;
    if (i < G4) bsum[i] = bih[i] + bhh[i];
    if (i < HDIM) c[i] = 0.0f;
    if (i < 2 * NSLOT) slots[i] = 0ull;
}

// ---------------------------------------------------------------------------
// prep: W_sum = fp16(W_ih + W_hh)
// ---------------------------------------------------------------------------
__global__ __launch_bounds__(256) void prep_wsum_h(const float* __restrict__ Wih,
                                                   const float* __restrict__ Whh,
                                                   __half* __restrict__ Wsum) {
    const int n8 = (G4 * HDIM) / 8;
    int idx = blockIdx.x * blockDim.x + threadIdx.x;
    int stride = gridDim.x * blockDim.x;
    const float4* a = (const float4*)Wih;
    const float4* b = (const float4*)Whh;
    for (int i = idx; i < n8; i += stride) {
        float4 a0 = a[2 * i], a1 = a[2 * i + 1];
        float4 b0 = b[2 * i], b1 = b[2 * i + 1];
        __half h[8];
        h[0] = __float2half(a0.x + b0.x);
        h[1] = __float2half(a0.y + b0.y);
        h[2] = __float2half(a0.z + b0.z);
        h[3] = __float2half(a0.w + b0.w);
        h[4] = __float2half(a1.x + b1.x);
        h[5] = __float2half(a1.y + b1.y);
        h[6] = __float2half(a1.z + b1.z);
        h[7] = __float2half(a1.w + b1.w);
        ((uint4*)Wsum)[i] = *(const uint4*)h;
    }
}

// ---------------------------------------------------------------------------
// t=0 step, exact fp32: gates = X @ W_ih.T + bsum (h0 = 0). Writes h->out[0],
// c->c[], and publishes h_0 into slots buf 0 with tag 1.
// ---------------------------------------------------------------------------
__global__ __launch_bounds__(256) void lstm_step_f32(const float* __restrict__ x,
                                                     const float* __restrict__ W,
                                                     const float* __restrict__ bsum,
                                                     float* __restrict__ c,
                                                     float* __restrict__ h_out,
                                                     unsigned long long* __restrict__ slots) {
    __shared__ float gates[4][8];
    __shared__ float h_sh[8];
    const int tid  = threadIdx.x;
    const int wave = tid >> 6;
    const int lane = tid & 63;
    const int j0   = blockIdx.x * 8;

    float4 xv[8];
    const float4* xp = (const float4*)x;
#pragma unroll
    for (int k = 0; k < 8; ++k) xv[k] = xp[lane + 64 * k];

    float acc[8];
#pragma unroll
    for (int j8 = 0; j8 < 8; ++j8) {
        const int R = wave * HDIM + j0 + j8;
        const float4* wr = (const float4*)(W + (size_t)R * HDIM);
        float a = 0.0f;
#pragma unroll
        for (int k = 0; k < 8; ++k) {
            float4 wv = wr[lane + 64 * k];
            a += wv.x * xv[k].x + wv.y * xv[k].y + wv.z * xv[k].z + wv.w * xv[k].w;
        }
        acc[j8] = a;
    }
#pragma unroll
    for (int j8 = 0; j8 < 8; ++j8) {
        float a = acc[j8];
#pragma unroll
        for (int off = 32; off > 0; off >>= 1) a += __shfl_down(a, off, 64);
        if (lane == 0) gates[wave][j8] = a + bsum[wave * HDIM + j0 + j8];
    }
    __syncthreads();
    if (tid < 8) {
        const int j = j0 + tid;
        const float si = 1.0f / (1.0f + expf(-gates[0][tid]));
        const float so = 1.0f / (1.0f + expf(-gates[3][tid]));
        const float tg = tanhf(gates[2][tid]);
        const float cn = si * tg;  // c0 = 0
        c[j] = cn;
        const float h = so * tanhf(cn);
        h_out[j]  = h;
        h_sh[tid] = h;
    }
    __syncthreads();
    if (tid < 4) {
        h2_t hp;
#if __has_builtin(__builtin_amdgcn_cvt_pkrtz)
        hp = __builtin_amdgcn_cvt_pkrtz(h_sh[2 * tid], h_sh[2 * tid + 1]);
#else
        hp = h2_t{(__fp16)h_sh[2 * tid], (__fp16)h_sh[2 * tid + 1]};
#endif
        unsigned long long pk = (1ull << 32) | (unsigned long long)__builtin_bit_cast(unsigned, hp);
        __hip_atomic_store(&slots[blockIdx.x * 4 + tid], pk,
                           __ATOMIC_RELAXED, __HIP_MEMORY_SCOPE_AGENT);
    }
}

// ---------------------------------------------------------------------------
// Round-2 per-step fp16 kernel — runtime fallback if cooperative launch fails.
// ---------------------------------------------------------------------------
__global__ __launch_bounds__(256) void lstm_step_h(const float* __restrict__ x,
                                                   const __half* __restrict__ W,
                                                   const float* __restrict__ bsum,
                                                   float* __restrict__ c,
                                                   float* __restrict__ h_out) {
    __shared__ float gates[4][8];
    const int tid  = threadIdx.x;
    const int wave = tid >> 6;
    const int lane = tid & 63;
    const int j0   = blockIdx.x * 8;

    float xv[32];
    const float4* xp = (const float4*)x;
#pragma unroll
    for (int k = 0; k < 4; ++k) {
        float4 a = xp[k * 128 + lane * 2];
        float4 b = xp[k * 128 + lane * 2 + 1];
        xv[k * 8 + 0] = a.x; xv[k * 8 + 1] = a.y; xv[k * 8 + 2] = a.z; xv[k * 8 + 3] = a.w;
        xv[k * 8 + 4] = b.x; xv[k * 8 + 5] = b.y; xv[k * 8 + 6] = b.z; xv[k * 8 + 7] = b.w;
    }
    float acc[8];
#pragma unroll
    for (int j8 = 0; j8 < 8; ++j8) {
        const int R = wave * HDIM + j0 + j8;
        const uint4* wr = (const uint4*)(W + (size_t)R * HDIM);
        float a = 0.0f;
#pragma unroll
        for (int k = 0; k < 4; ++k) {
            uint4 wv = wr[k * 64 + lane];
            const __half* hh = (const __half*)&wv;
#pragma unroll
            for (int e = 0; e < 8; ++e)
                a = fmaf(__half2float(hh[e]), xv[k * 8 + e], a);
        }
        acc[j8] = a;
    }
#pragma unroll
    for (int j8 = 0; j8 < 8; ++j8) {
        float a = acc[j8];
#pragma unroll
        for (int off = 32; off > 0; off >>= 1) a += __shfl_down(a, off, 64);
        if (lane == 0) gates[wave][j8] = a + bsum[wave * HDIM + j0 + j8];
    }
    __syncthreads();
    if (tid < 8) {
        const int j = j0 + tid;
        const float si = 1.0f / (1.0f + expf(-gates[0][tid]));
        const float sf = 1.0f / (1.0f + expf(-gates[1][tid]));
        const float so = 1.0f / (1.0f + expf(-gates[3][tid]));
        const float tg = tanhf(gates[2][tid]);
        const float cn = sf * c[j] + si * tg;
        c[j]     = cn;
        h_out[j] = so * tanhf(cn);
    }
}

// ---------------------------------------------------------------------------
// Persistent kernel, steps 1..T-1. Weights resident in regs (128 VGPR/lane).
// NO grid barrier, NO fences: h exchanged via self-validating 64-bit slots
// {2 x fp16 h, tag}, written/read with RELAXED agent-scope atomics (coherent
// at L3; value+tag arrive atomically). Double-buffered by t&1; producer at
// step t stores tag t+1 into buf t&1; consumer at step t polls tag t in
// buf (t-1)&1. Dependency chain bounds producers to <=1 step ahead.
// ---------------------------------------------------------------------------
__global__ __launch_bounds__(256, 1) void lstm_persist(const __half* __restrict__ W,
                                                       const float* __restrict__ bsum,
                                                       const float* __restrict__ c0,
                                                       float* __restrict__ out,
                                                       unsigned long long* __restrict__ slots,
                                                       int T) {
    const int tid  = threadIdx.x;
    const int wave = tid >> 6;
    const int lane = tid & 63;
    const int j0   = blockIdx.x * 8;

    // One-time: weights into registers (8 rows x 4 uint4 = 128 VGPRs/lane).
    uint4 w[8][4];
#pragma unroll
    for (int j8 = 0; j8 < 8; ++j8) {
        const size_t R = (size_t)(wave * HDIM + j0 + j8);
        const uint4* wr = (const uint4*)(W + R * HDIM);
#pragma unroll
        for (int e = 0; e < 4; ++e) w[j8][e] = wr[lane + 64 * e];
    }
    float bias[8];
#pragma unroll
    for (int j8 = 0; j8 < 8; ++j8) bias[j8] = bsum[wave * HDIM + j0 + j8];

    __shared__ float c_sh[8];
    __shared__ float gates[4][8];
    __shared__ float h_sh[8];
    if (tid < 8) c_sh[tid] = c0[j0 + tid];
    __syncthreads();

    for (int t = 1; t < T; ++t) {
        // ---- poll the 16 slots this lane needs (h_{t-1}, tag t) ----
        const unsigned long long* sl = slots + (size_t)((t - 1) & 1) * NSLOT;
        const unsigned tg = (unsigned)t;
        unsigned long long v[16];
#pragma unroll
        for (int i = 0; i < 16; ++i)
            v[i] = __hip_atomic_load(&sl[(lane + 64 * (i >> 2)) * 4 + (i & 3)],
                                     __ATOMIC_RELAXED, __HIP_MEMORY_SCOPE_AGENT);
        while (true) {
            unsigned bad = 0;
#pragma unroll
            for (int i = 0; i < 16; ++i)
                if ((unsigned)(v[i] >> 32) != tg) bad |= (1u << i);
            if (!bad) break;
            __builtin_amdgcn_s_sleep(1);
#pragma unroll
            for (int i = 0; i < 16; ++i)
                if (bad & (1u << i))
                    v[i] = __hip_atomic_load(&sl[(lane + 64 * (i >> 2)) * 4 + (i & 3)],
                                             __ATOMIC_RELAXED, __HIP_MEMORY_SCOPE_AGENT);
        }

        // ---- dot: 8 rows x 32 cols per lane, fp16 pairs ----
        float acc[8] = {0.f, 0.f, 0.f, 0.f, 0.f, 0.f, 0.f, 0.f};
#pragma unroll
        for (int i = 0; i < 16; ++i) {
            const h2_t xh = __builtin_bit_cast(h2_t, (unsigned)(v[i] & 0xffffffffull));
            const int e = i >> 2, p = i & 3;
#pragma unroll
            for (int j8 = 0; j8 < 8; ++j8) {
                const h2_t* wh = (const h2_t*)&w[j8][e];
#if __has_builtin(__builtin_amdgcn_fdot2)
                acc[j8] = __builtin_amdgcn_fdot2(wh[p], xh, acc[j8], false);
#else
                acc[j8] = fmaf((float)wh[p][0], (float)xh[0],
                               fmaf((float)wh[p][1], (float)xh[1], acc[j8]));
#endif
            }
        }

#pragma unroll
        for (int j8 = 0; j8 < 8; ++j8) {
            float a = acc[j8];
#pragma unroll
            for (int off = 32; off > 0; off >>= 1) a += __shfl_down(a, off, 64);
            if (lane == 0) gates[wave][j8] = a + bias[j8];
        }
        __syncthreads();

        if (tid < 8) {
            const float si = 1.0f / (1.0f + expf(-gates[0][tid]));
            const float sf = 1.0f / (1.0f + expf(-gates[1][tid]));
            const float so = 1.0f / (1.0f + expf(-gates[3][tid]));
            const float tg2 = tanhf(gates[2][tid]);
            const float cn = sf * c_sh[tid] + si * tg2;
            c_sh[tid] = cn;
            const float h = so * tanhf(cn);
            out[(size_t)t * HDIM + j0 + tid] = h;
            h_sh[tid] = h;
        }
        __syncthreads();

        // ---- publish h_t: buf t&1, tag t+1 ----
        if (tid < 4) {
            h2_t hp;
#if __has_builtin(__builtin_amdgcn_cvt_pkrtz)
            hp = __builtin_amdgcn_cvt_pkrtz(h_sh[2 * tid], h_sh[2 * tid + 1]);
#else
            hp = h2_t{(__fp16)h_sh[2 * tid], (__fp16)h_sh[2 * tid + 1]};
#endif
            unsigned long long pk = ((unsigned long long)(unsigned)(t + 1) << 32)
                                  | (unsigned long long)__builtin_bit_cast(unsigned, hp);
            __hip_atomic_store(&slots[(size_t)(t & 1) * NSLOT + blockIdx.x * 4 + tid], pk,
                               __ATOMIC_RELAXED, __HIP_MEMORY_SCOPE_AGENT);
        }
    }
}

// ---------------------------------------------------------------------------
extern "C" void kernel_launch(void* const* d_in, const int* in_sizes, int n_in,
                              void* d_out, int out_size, void* d_ws, size_t ws_size,
                              hipStream_t stream) {
    const float* X   = (const float*)d_in[0];
    const float* Wih = (const float*)d_in[1];
    const float* Whh = (const float*)d_in[2];
    const float* bih = (const float*)d_in[3];
    const float* bhh = (const float*)d_in[4];
    float* out = (float*)d_out;

    int T = out_size / HDIM;  // 512

    // ws: [W_sum fp16 33.55 MB][b_sum 32 KB][c 8 KB][slots 16 KB]
    const size_t wsum_bytes = (size_t)G4 * HDIM * sizeof(__half);
    char* ws = (char*)d_ws;
    __half* Wsum = (__half*)ws;
    float*  bsum = (float*)(ws + wsum_bytes);
    float*  c    = bsum + G4;
    unsigned long long* slots = (unsigned long long*)(c + HDIM);

    prep_small<<<(G4 + 255) / 256, 256, 0, stream>>>(bih, bhh, bsum, c, slots);
    prep_wsum_h<<<2048, 256, 0, stream>>>(Wih, Whh, Wsum);

    // t = 0: exact fp32, publishes h_0 into slots (buf 0, tag 1).
    lstm_step_f32<<<256, 256, 0, stream>>>(X, Wih, bsum, c, out, slots);

    // t >= 1: persistent kernel, weights in regs, fence-free tagged dataflow.
    void* args[] = {(void*)&Wsum, (void*)&bsum, (void*)&c, (void*)&out,
                    (void*)&slots, (void*)&T};
    hipError_t err = hipLaunchCooperativeKernel((const void*)lstm_persist,
                                                dim3(NBLK), dim3(256), args, 0, stream);
    if (err != hipSuccess) {
        // Fallback: proven round-2 per-step loop.
        for (int t = 1; t < T; ++t) {
            const float* hprev = out + (size_t)(t - 1) * HDIM;
            float* hnext = out + (size_t)t * HDIM;
            lstm_step_h<<<256, 256, 0, stream>>>(hprev, Wsum, bsum, c, hnext);
        }
    }
}

// Round 6
// 2269.053 us; speedup vs baseline: 6.8255x; 1.1885x over previous
//
#include <hip/hip_runtime.h>
#include <hip/hip_fp16.h>
#include <math.h>

#define HDIM 2048
#define G4   (4 * HDIM)   // 8192 gate rows
#define NBLK 128          // persistent grid
#define TPB  512          // threads per block (8 waves)
#define NSLOT 1024        // h slots per buffer (2 fp16 per slot)

// __builtin_amdgcn_cvt_pkrtz / __builtin_amdgcn_fdot2 use the __fp16 vector
// type (NOT _Float16 — they don't implicitly convert).
typedef __fp16 h2_t __attribute__((ext_vector_type(2)));

// ---------------------------------------------------------------------------
// prep: b_sum = b_ih + b_hh ; c = 0 ; tagged h slots = 0 (tag 0 = invalid)
// ---------------------------------------------------------------------------
__global__ __launch_bounds__(256) void prep_small(const float* __restrict__ bih,
                                                  const float* __restrict__ bhh,
                                                  float* __restrict__ bsum,
                                                  float* __restrict__ c,
                                                  unsigned long long* __restrict__ slots) {
    int i = blockIdx.x * blockDim.x + threadIdx.x;
    if (i < G4) bsum[i] = bih[i] + bhh[i];
    if (i < HDIM) c[i] = 0.0f;
    if (i < 2 * NSLOT) slots[i] = 0ull;
}

// ---------------------------------------------------------------------------
// prep: W_sum = fp16(W_ih + W_hh)
// ---------------------------------------------------------------------------
__global__ __launch_bounds__(256) void prep_wsum_h(const float* __restrict__ Wih,
                                                   const float* __restrict__ Whh,
                                                   __half* __restrict__ Wsum) {
    const int n8 = (G4 * HDIM) / 8;
    int idx = blockIdx.x * blockDim.x + threadIdx.x;
    int stride = gridDim.x * blockDim.x;
    const float4* a = (const float4*)Wih;
    const float4* b = (const float4*)Whh;
    for (int i = idx; i < n8; i += stride) {
        float4 a0 = a[2 * i], a1 = a[2 * i + 1];
        float4 b0 = b[2 * i], b1 = b[2 * i + 1];
        __half h[8];
        h[0] = __float2half(a0.x + b0.x);
        h[1] = __float2half(a0.y + b0.y);
        h[2] = __float2half(a0.z + b0.z);
        h[3] = __float2half(a0.w + b0.w);
        h[4] = __float2half(a1.x + b1.x);
        h[5] = __float2half(a1.y + b1.y);
        h[6] = __float2half(a1.z + b1.z);
        h[7] = __float2half(a1.w + b1.w);
        ((uint4*)Wsum)[i] = *(const uint4*)h;
    }
}

// ---------------------------------------------------------------------------
// t=0 step, exact fp32: gates = X @ W_ih.T + bsum (h0 = 0). Writes h->out[0],
// c->c[], and publishes h_0 into slots buf 0 with tag 1. 256 blocks x 256.
// ---------------------------------------------------------------------------
__global__ __launch_bounds__(256) void lstm_step_f32(const float* __restrict__ x,
                                                     const float* __restrict__ W,
                                                     const float* __restrict__ bsum,
                                                     float* __restrict__ c,
                                                     float* __restrict__ h_out,
                                                     unsigned long long* __restrict__ slots) {
    __shared__ float gates[4][8];
    __shared__ float h_sh[8];
    const int tid  = threadIdx.x;
    const int wave = tid >> 6;
    const int lane = tid & 63;
    const int j0   = blockIdx.x * 8;

    float4 xv[8];
    const float4* xp = (const float4*)x;
#pragma unroll
    for (int k = 0; k < 8; ++k) xv[k] = xp[lane + 64 * k];

    float acc[8];
#pragma unroll
    for (int j8 = 0; j8 < 8; ++j8) {
        const int R = wave * HDIM + j0 + j8;
        const float4* wr = (const float4*)(W + (size_t)R * HDIM);
        float a = 0.0f;
#pragma unroll
        for (int k = 0; k < 8; ++k) {
            float4 wv = wr[lane + 64 * k];
            a += wv.x * xv[k].x + wv.y * xv[k].y + wv.z * xv[k].z + wv.w * xv[k].w;
        }
        acc[j8] = a;
    }
#pragma unroll
    for (int j8 = 0; j8 < 8; ++j8) {
        float a = acc[j8];
#pragma unroll
        for (int off = 32; off > 0; off >>= 1) a += __shfl_down(a, off, 64);
        if (lane == 0) gates[wave][j8] = a + bsum[wave * HDIM + j0 + j8];
    }
    __syncthreads();
    if (tid < 8) {
        const int j = j0 + tid;
        const float si = 1.0f / (1.0f + expf(-gates[0][tid]));
        const float so = 1.0f / (1.0f + expf(-gates[3][tid]));
        const float tg = tanhf(gates[2][tid]);
        const float cn = si * tg;  // c0 = 0
        c[j] = cn;
        const float h = so * tanhf(cn);
        h_out[j]  = h;
        h_sh[tid] = h;
    }
    __syncthreads();
    if (tid < 4) {
        h2_t hp;
#if __has_builtin(__builtin_amdgcn_cvt_pkrtz)
        hp = __builtin_amdgcn_cvt_pkrtz(h_sh[2 * tid], h_sh[2 * tid + 1]);
#else
        hp = h2_t{(__fp16)h_sh[2 * tid], (__fp16)h_sh[2 * tid + 1]};
#endif
        unsigned long long pk = (1ull << 32) | (unsigned long long)__builtin_bit_cast(unsigned, hp);
        __hip_atomic_store(&slots[blockIdx.x * 4 + tid], pk,
                           __ATOMIC_RELAXED, __HIP_MEMORY_SCOPE_AGENT);
    }
}

// ---------------------------------------------------------------------------
// Round-2 per-step fp16 kernel — runtime fallback if cooperative launch fails.
// ---------------------------------------------------------------------------
__global__ __launch_bounds__(256) void lstm_step_h(const float* __restrict__ x,
                                                   const __half* __restrict__ W,
                                                   const float* __restrict__ bsum,
                                                   float* __restrict__ c,
                                                   float* __restrict__ h_out) {
    __shared__ float gates[4][8];
    const int tid  = threadIdx.x;
    const int wave = tid >> 6;
    const int lane = tid & 63;
    const int j0   = blockIdx.x * 8;

    float xv[32];
    const float4* xp = (const float4*)x;
#pragma unroll
    for (int k = 0; k < 4; ++k) {
        float4 a = xp[k * 128 + lane * 2];
        float4 b = xp[k * 128 + lane * 2 + 1];
        xv[k * 8 + 0] = a.x; xv[k * 8 + 1] = a.y; xv[k * 8 + 2] = a.z; xv[k * 8 + 3] = a.w;
        xv[k * 8 + 4] = b.x; xv[k * 8 + 5] = b.y; xv[k * 8 + 6] = b.z; xv[k * 8 + 7] = b.w;
    }
    float acc[8];
#pragma unroll
    for (int j8 = 0; j8 < 8; ++j8) {
        const int R = wave * HDIM + j0 + j8;
        const uint4* wr = (const uint4*)(W + (size_t)R * HDIM);
        float a = 0.0f;
#pragma unroll
        for (int k = 0; k < 4; ++k) {
            uint4 wv = wr[k * 64 + lane];
            const __half* hh = (const __half*)&wv;
#pragma unroll
            for (int e = 0; e < 8; ++e)
                a = fmaf(__half2float(hh[e]), xv[k * 8 + e], a);
        }
        acc[j8] = a;
    }
#pragma unroll
    for (int j8 = 0; j8 < 8; ++j8) {
        float a = acc[j8];
#pragma unroll
        for (int off = 32; off > 0; off >>= 1) a += __shfl_down(a, off, 64);
        if (lane == 0) gates[wave][j8] = a + bsum[wave * HDIM + j0 + j8];
    }
    __syncthreads();
    if (tid < 8) {
        const int j = j0 + tid;
        const float si = 1.0f / (1.0f + expf(-gates[0][tid]));
        const float sf = 1.0f / (1.0f + expf(-gates[1][tid]));
        const float so = 1.0f / (1.0f + expf(-gates[3][tid]));
        const float tg = tanhf(gates[2][tid]);
        const float cn = sf * c[j] + si * tg;
        c[j]     = cn;
        h_out[j] = so * tanhf(cn);
    }
}

// ---------------------------------------------------------------------------
// Persistent kernel, steps 1..T-1. 128 blocks x 512 threads (8 waves).
// Block owns h[16b..16b+16); wave w = gate (w>>1), rows (w&1)*8..+8.
// Weights resident in regs (128 VGPR/lane). Fence-free tagged dataflow as in
// round 5, but polling is DEDUPLICATED: wave w polls slots [w*128, w*128+128)
// (2 slots/lane), payloads go to LDS, all waves read x from LDS. Poll
// transactions/round: 128*512*2 = 131K vs round 5's 1.05M (8x cut).
// ---------------------------------------------------------------------------
__global__ __launch_bounds__(TPB, 2) void lstm_persist(const __half* __restrict__ W,
                                                       const float* __restrict__ bsum,
                                                       const float* __restrict__ c0,
                                                       float* __restrict__ out,
                                                       unsigned long long* __restrict__ slots,
                                                       int T) {
    const int tid  = threadIdx.x;
    const int wave = tid >> 6;        // 0..7
    const int lane = tid & 63;
    const int gate = wave >> 1;       // 0..3
    const int rsub = (wave & 1) * 8;  // row offset within block's 16
    const int j0   = blockIdx.x * 16;

    // One-time: weights into registers (8 rows x 4 uint4 = 128 VGPRs/lane).
    uint4 w[8][4];
#pragma unroll
    for (int j8 = 0; j8 < 8; ++j8) {
        const size_t R = (size_t)gate * HDIM + j0 + rsub + j8;
        const uint4* wr = (const uint4*)(W + R * HDIM);
#pragma unroll
        for (int e = 0; e < 4; ++e) w[j8][e] = wr[lane + 64 * e];
    }
    float bias[8];
#pragma unroll
    for (int j8 = 0; j8 < 8; ++j8) bias[j8] = bsum[gate * HDIM + j0 + rsub + j8];

    __shared__ __align__(16) unsigned lds_x[NSLOT];  // h pairs (fp16x2 payload)
    __shared__ float gates_sh[64];                   // [gate*16 + jj]
    __shared__ float c_sh[16];
    if (tid < 16) c_sh[tid] = c0[j0 + tid];
    __syncthreads();

    for (int t = 1; t < T; ++t) {
        // ---- dedup poll: wave w owns slots [w*128, w*128+128), 2/lane ----
        const unsigned long long* sl = slots + (size_t)((t - 1) & 1) * NSLOT;
        const unsigned tg = (unsigned)t;
        const int s0 = wave * 128 + lane;
        const int s1 = s0 + 64;
        unsigned long long v0 = __hip_atomic_load(&sl[s0], __ATOMIC_RELAXED,
                                                  __HIP_MEMORY_SCOPE_AGENT);
        unsigned long long v1 = __hip_atomic_load(&sl[s1], __ATOMIC_RELAXED,
                                                  __HIP_MEMORY_SCOPE_AGENT);
        int spin = 0;
        while (((unsigned)(v0 >> 32) != tg) | ((unsigned)(v1 >> 32) != tg)) {
            if (spin++) __builtin_amdgcn_s_sleep(1);
            if ((unsigned)(v0 >> 32) != tg)
                v0 = __hip_atomic_load(&sl[s0], __ATOMIC_RELAXED,
                                       __HIP_MEMORY_SCOPE_AGENT);
            if ((unsigned)(v1 >> 32) != tg)
                v1 = __hip_atomic_load(&sl[s1], __ATOMIC_RELAXED,
                                       __HIP_MEMORY_SCOPE_AGENT);
        }
        lds_x[s0] = (unsigned)v0;
        lds_x[s1] = (unsigned)v1;
        __syncthreads();

        // ---- dot: 8 rows x 32 cols per lane, x pairs from LDS ----
        float acc[8] = {0.f, 0.f, 0.f, 0.f, 0.f, 0.f, 0.f, 0.f};
#pragma unroll
        for (int e = 0; e < 4; ++e) {
            const uint4 xq = *(const uint4*)&lds_x[(lane + 64 * e) * 4];
            const unsigned xs[4] = {xq.x, xq.y, xq.z, xq.w};
#pragma unroll
            for (int p = 0; p < 4; ++p) {
                const h2_t xh = __builtin_bit_cast(h2_t, xs[p]);
#pragma unroll
                for (int j8 = 0; j8 < 8; ++j8) {
                    const h2_t* wh = (const h2_t*)&w[j8][e];
#if __has_builtin(__builtin_amdgcn_fdot2)
                    acc[j8] = __builtin_amdgcn_fdot2(wh[p], xh, acc[j8], false);
#else
                    acc[j8] = fmaf((float)wh[p][0], (float)xh[0],
                                   fmaf((float)wh[p][1], (float)xh[1], acc[j8]));
#endif
                }
            }
        }

#pragma unroll
        for (int j8 = 0; j8 < 8; ++j8) {
            float a = acc[j8];
#pragma unroll
            for (int off = 32; off > 0; off >>= 1) a += __shfl_down(a, off, 64);
            if (lane == 0) gates_sh[gate * 16 + rsub + j8] = a + bias[j8];
        }
        __syncthreads();

        // ---- pointwise + immediate publish (tid<8, 2 h-elems each) ----
        if (tid < 8) {
            float h2v[2];
#pragma unroll
            for (int q = 0; q < 2; ++q) {
                const int jj = 2 * tid + q;
                const float si = 1.0f / (1.0f + expf(-gates_sh[jj]));
                const float sf = 1.0f / (1.0f + expf(-gates_sh[16 + jj]));
                const float so = 1.0f / (1.0f + expf(-gates_sh[48 + jj]));
                const float tg2 = tanhf(gates_sh[32 + jj]);
                const float cn = sf * c_sh[jj] + si * tg2;
                c_sh[jj] = cn;
                h2v[q] = so * tanhf(cn);
            }
            h2_t hp;
#if __has_builtin(__builtin_amdgcn_cvt_pkrtz)
            hp = __builtin_amdgcn_cvt_pkrtz(h2v[0], h2v[1]);
#else
            hp = h2_t{(__fp16)h2v[0], (__fp16)h2v[1]};
#endif
            unsigned long long pk = ((unsigned long long)(unsigned)(t + 1) << 32)
                                  | (unsigned long long)__builtin_bit_cast(unsigned, hp);
            __hip_atomic_store(&slots[(size_t)(t & 1) * NSLOT + blockIdx.x * 8 + tid], pk,
                               __ATOMIC_RELAXED, __HIP_MEMORY_SCOPE_AGENT);
            // out[] write is off the critical path — after publish.
            *(float2*)&out[(size_t)t * HDIM + j0 + 2 * tid] = make_float2(h2v[0], h2v[1]);
        }
        // No trailing barrier: next-iter lds_x writes are safe (all waves
        // passed the gates barrier ⇒ all dot reads of lds_x completed), and
        // gates_sh is only rewritten after the next post-poll barrier.
    }
}

// ---------------------------------------------------------------------------
extern "C" void kernel_launch(void* const* d_in, const int* in_sizes, int n_in,
                              void* d_out, int out_size, void* d_ws, size_t ws_size,
                              hipStream_t stream) {
    const float* X   = (const float*)d_in[0];
    const float* Wih = (const float*)d_in[1];
    const float* Whh = (const float*)d_in[2];
    const float* bih = (const float*)d_in[3];
    const float* bhh = (const float*)d_in[4];
    float* out = (float*)d_out;

    int T = out_size / HDIM;  // 512

    // ws: [W_sum fp16 33.55 MB][b_sum 32 KB][c 8 KB][slots 16 KB]
    const size_t wsum_bytes = (size_t)G4 * HDIM * sizeof(__half);
    char* ws = (char*)d_ws;
    __half* Wsum = (__half*)ws;
    float*  bsum = (float*)(ws + wsum_bytes);
    float*  c    = bsum + G4;
    unsigned long long* slots = (unsigned long long*)(c + HDIM);

    prep_small<<<(G4 + 255) / 256, 256, 0, stream>>>(bih, bhh, bsum, c, slots);
    prep_wsum_h<<<2048, 256, 0, stream>>>(Wih, Whh, Wsum);

    // t = 0: exact fp32, publishes h_0 into slots (buf 0, tag 1).
    lstm_step_f32<<<256, 256, 0, stream>>>(X, Wih, bsum, c, out, slots);

    // t >= 1: persistent kernel, weights in regs, dedup fence-free dataflow.
    void* args[] = {(void*)&Wsum, (void*)&bsum, (void*)&c, (void*)&out,
                    (void*)&slots, (void*)&T};
    hipError_t err = hipLaunchCooperativeKernel((const void*)lstm_persist,
                                                dim3(NBLK), dim3(TPB), args, 0, stream);
    if (err != hipSuccess) {
        // Fallback: proven round-2 per-step loop.
        for (int t = 1; t < T; ++t) {
            const float* hprev = out + (size_t)(t - 1) * HDIM;
            float* hnext = out + (size_t)t * HDIM;
            lstm_step_h<<<256, 256, 0, stream>>>(hprev, Wsum, bsum, c, hnext);
        }
    }
}